// Round 2
// baseline (254.756 us; speedup 1.0000x reference)
//
#include <hip/hip_runtime.h>
#include <math.h>

#define T_LEN 220500
#define CHUNK 256
#define WARM  1024

// One thread per output chunk. Thread scans the IIR from (chunk_start - WARM)
// with zero state; the transient from the wrong initial state decays by
// r^WARM ~= 1e-9 (lowpass pole r ~= 0.9801), far below the 9.4e-3 threshold.
__global__ __launch_bounds__(256) void bandpass_kernel(
    const float* __restrict__ x,
    const int* __restrict__ sr_p,
    const float* __restrict__ fl_p,
    const float* __restrict__ fh_p,
    float* __restrict__ out,
    int nchunks)
{
    const int seq = blockIdx.y;
    const int chunk = blockIdx.x * blockDim.x + threadIdx.x;
    if (chunk >= nchunks) return;

    // ---- biquad coefficients (computed in double, cast to float) ----
    const double sr = (double)sr_p[0];
    const double twoQ = 2.0 * 0.707;   // torchaudio default Q

    // lowpass @ cutoff_low
    double w0 = 2.0 * M_PI * (double)fl_p[0] / sr;
    double cw = cos(w0);
    double al = sin(w0) / twoQ;
    double a0 = 1.0 + al;
    const float lb0  = (float)(((1.0 - cw) * 0.5) / a0);
    const float lb1  = (float)((1.0 - cw) / a0);
    const float lb2  = lb0;
    const float lna1 = (float)((2.0 * cw) / a0);       // = -a1/a0
    const float lna2 = (float)(-(1.0 - al) / a0);      // = -a2/a0

    // highpass @ cutoff_high
    w0 = 2.0 * M_PI * (double)fh_p[0] / sr;
    cw = cos(w0);
    al = sin(w0) / twoQ;
    a0 = 1.0 + al;
    const float hb0  = (float)(((1.0 + cw) * 0.5) / a0);
    const float hb1  = (float)(-(1.0 + cw) / a0);
    const float hb2  = hb0;
    const float hna1 = (float)((2.0 * cw) / a0);
    const float hna2 = (float)(-(1.0 - al) / a0);

    const float* __restrict__ xs = x   + (size_t)seq * T_LEN;
    float*       __restrict__ os = out + (size_t)seq * T_LEN;

    const int s = chunk * CHUNK;                 // first output sample
    const int e = min(s + CHUNK, T_LEN);         // one past last output
    const int w = max(0, s - WARM);              // scan start (zero state)

    // FIR history at scan start (exact: these are real input samples, or the
    // zero padding at the very beginning of the sequence)
    float x1 = 0.f, x2 = 0.f;
    if (w > 0) { x1 = xs[w - 1]; x2 = xs[w - 2]; }

    float ly1 = 0.f, ly2 = 0.f;   // lowpass  state
    float hy1 = 0.f, hy2 = 0.f;   // highpass state

    // All of w, s, e, T_LEN are multiples of 4 -> aligned float4 I/O in-bounds.
    for (int n = w; n < e; n += 4) {
        const float4 xv = *(const float4*)(xs + n);
        float xin[4] = {xv.x, xv.y, xv.z, xv.w};
        float o[4];
#pragma unroll
        for (int k = 0; k < 4; ++k) {
            const float xc = xin[k];
            // lowpass
            float ffl = fmaf(lb0, xc, fmaf(lb1, x1, lb2 * x2));
            float yl  = fmaf(lna2, ly2, fmaf(lna1, ly1, ffl));
            // highpass (independent chain -> ILP with lowpass)
            float ffh = fmaf(hb0, xc, fmaf(hb1, x1, hb2 * x2));
            float yh  = fmaf(hna2, hy2, fmaf(hna1, hy1, ffh));
            ly2 = ly1; ly1 = yl;
            hy2 = hy1; hy1 = yh;
            x2 = x1; x1 = xc;
            o[k] = yl - yh;
        }
        if (n >= s) {
            *(float4*)(os + n) = make_float4(o[0], o[1], o[2], o[3]);
        }
    }
}

extern "C" void kernel_launch(void* const* d_in, const int* in_sizes, int n_in,
                              void* d_out, int out_size, void* d_ws, size_t ws_size,
                              hipStream_t stream) {
    const float* x  = (const float*)d_in[0];
    const int*   sr = (const int*)d_in[1];
    const float* fl = (const float*)d_in[2];
    const float* fh = (const float*)d_in[3];
    float* out = (float*)d_out;

    const int nseq    = in_sizes[0] / T_LEN;                   // 64
    const int nchunks = (T_LEN + CHUNK - 1) / CHUNK;           // 862

    dim3 block(256);
    dim3 grid((nchunks + block.x - 1) / block.x, nseq);
    hipLaunchKernelGGL(bandpass_kernel, grid, block, 0, stream,
                       x, sr, fl, fh, out, nchunks);
}

// Round 3
// 158.021 us; speedup vs baseline: 1.6122x; 1.6122x over previous
//
#include <hip/hip_runtime.h>
#include <math.h>

#define T_LEN   220500
#define CHUNK   64
#define WARM    512
#define CPB     256                          // chunks per block == threads per block
#define REG     (CPB*CHUNK + WARM + 4)       // 16900 floats staged per block
#define SLOT(j) ((j) + ((j) >> 6))           // +1 float pad per 64 -> 2-way banks (free)
#define LDSF    (REG + (REG >> 6))           // 17164 floats = 68.7 KB

// Each thread owns one 64-sample output chunk; scans from 512 samples earlier
// with zero state (lowpass pole r=0.9801 -> transient ~5e-4 << 9.4e-3 thr).
// Block stages the union of all its threads' windows into LDS with coalesced
// float4 global loads; scan reads come from LDS (padded, conflict-free).
__global__ __launch_bounds__(256) void bandpass_kernel(
    const float* __restrict__ x,
    const int* __restrict__ sr_p,
    const float* __restrict__ fl_p,
    const float* __restrict__ fh_p,
    float* __restrict__ out)
{
    __shared__ float lds[LDSF];

    const int tid = threadIdx.x;
    const int seq = blockIdx.y;
    const int bx  = blockIdx.x;

    // ---- biquad coefficients (double, cast to float; one-time cost) ----
    const double sr = (double)sr_p[0];
    const double twoQ = 2.0 * 0.707;

    double w0 = 2.0 * M_PI * (double)fl_p[0] / sr;
    double cw = cos(w0);
    double al = sin(w0) / twoQ;
    double a0 = 1.0 + al;
    const float lb0  = (float)(((1.0 - cw) * 0.5) / a0);
    const float lb1  = (float)((1.0 - cw) / a0);
    const float lb2  = lb0;
    const float lna1 = (float)((2.0 * cw) / a0);     // = -a1/a0
    const float lna2 = (float)(-(1.0 - al) / a0);    // = -a2/a0

    w0 = 2.0 * M_PI * (double)fh_p[0] / sr;
    cw = cos(w0);
    al = sin(w0) / twoQ;
    a0 = 1.0 + al;
    const float hb0  = (float)(((1.0 + cw) * 0.5) / a0);
    const float hb1  = (float)(-(1.0 + cw) / a0);
    const float hb2  = hb0;
    const float hna1 = (float)((2.0 * cw) / a0);
    const float hna2 = (float)(-(1.0 - al) / a0);

    const float* __restrict__ xs = x   + (size_t)seq * T_LEN;
    float*       __restrict__ os = out + (size_t)seq * T_LEN;

    const int out_g0 = bx * (CPB * CHUNK);       // first output sample of block
    const int g0     = out_g0 - (WARM + 4);      // global sample at region coord 0
                                                 // (mult of 4 -> float4-aligned)

    // ---- stage [g0, g0+REG) into LDS, coalesced; OOB -> 0 ----
    for (int i4 = tid; i4 < REG / 4; i4 += CPB) {
        const int j = i4 * 4;
        const int g = g0 + j;
        float4 v;
        if (g >= 0 && g + 3 < T_LEN) {
            v = *(const float4*)(xs + g);
        } else {
            v.x = (g + 0 >= 0 && g + 0 < T_LEN) ? xs[g + 0] : 0.f;
            v.y = (g + 1 >= 0 && g + 1 < T_LEN) ? xs[g + 1] : 0.f;
            v.z = (g + 2 >= 0 && g + 2 < T_LEN) ? xs[g + 2] : 0.f;
            v.w = (g + 3 >= 0 && g + 3 < T_LEN) ? xs[g + 3] : 0.f;
        }
        const int s = SLOT(j);   // j..j+3 never cross a 64-boundary
        lds[s + 0] = v.x; lds[s + 1] = v.y; lds[s + 2] = v.z; lds[s + 3] = v.w;
    }
    __syncthreads();

    const int chunk = bx * CPB + tid;
    const int gout  = chunk * CHUNK;
    if (gout >= T_LEN) return;                   // after barrier: safe

    const int jbase = tid * CHUNK + 4;           // region coord of scan start

    // FIR history (real samples or staged zeros at sequence start)
    float x1 = lds[SLOT(jbase - 1)];
    float x2 = lds[SLOT(jbase - 2)];

    float ly1 = 0.f, ly2 = 0.f;
    float hy1 = 0.f, hy2 = 0.f;

    // ---- warm-up: state only ----
#pragma unroll 8
    for (int t = 0; t < WARM; ++t) {
        const float xc = lds[SLOT(jbase + t)];
        const float ffl = fmaf(lb0, xc, fmaf(lb1, x1, lb2 * x2));
        const float yl  = fmaf(lna2, ly2, fmaf(lna1, ly1, ffl));
        const float ffh = fmaf(hb0, xc, fmaf(hb1, x1, hb2 * x2));
        const float yh  = fmaf(hna2, hy2, fmaf(hna1, hy1, ffh));
        ly2 = ly1; ly1 = yl;
        hy2 = hy1; hy1 = yh;
        x2 = x1; x1 = xc;
    }

    // ---- output: 64 samples ----
    const int jout = jbase + WARM;
    const bool full = (gout + CHUNK <= T_LEN);
    for (int t = 0; t < CHUNK; t += 4) {
        float o[4];
#pragma unroll
        for (int k = 0; k < 4; ++k) {
            const float xc = lds[SLOT(jout + t + k)];
            const float ffl = fmaf(lb0, xc, fmaf(lb1, x1, lb2 * x2));
            const float yl  = fmaf(lna2, ly2, fmaf(lna1, ly1, ffl));
            const float ffh = fmaf(hb0, xc, fmaf(hb1, x1, hb2 * x2));
            const float yh  = fmaf(hna2, hy2, fmaf(hna1, hy1, ffh));
            ly2 = ly1; ly1 = yl;
            hy2 = hy1; hy1 = yh;
            x2 = x1; x1 = xc;
            o[k] = yl - yh;
        }
        if (full) {
            *(float4*)(os + gout + t) = make_float4(o[0], o[1], o[2], o[3]);
        } else {
#pragma unroll
            for (int k = 0; k < 4; ++k)
                if (gout + t + k < T_LEN) os[gout + t + k] = o[k];
        }
    }
}

extern "C" void kernel_launch(void* const* d_in, const int* in_sizes, int n_in,
                              void* d_out, int out_size, void* d_ws, size_t ws_size,
                              hipStream_t stream) {
    const float* x  = (const float*)d_in[0];
    const int*   sr = (const int*)d_in[1];
    const float* fl = (const float*)d_in[2];
    const float* fh = (const float*)d_in[3];
    float* outp = (float*)d_out;

    const int nseq    = in_sizes[0] / T_LEN;                    // 64
    const int nchunks = (T_LEN + CHUNK - 1) / CHUNK;            // 3446
    const int bx      = (nchunks + CPB - 1) / CPB;              // 14

    dim3 block(CPB);
    dim3 grid(bx, nseq);
    hipLaunchKernelGGL(bandpass_kernel, grid, block, 0, stream,
                       x, sr, fl, fh, outp);
}

// Round 4
// 155.229 us; speedup vs baseline: 1.6412x; 1.0180x over previous
//
#include <hip/hip_runtime.h>
#include <math.h>

#define T_LEN   220500
#define SEG     64                      // samples per thread (16 float4 in VGPRs)
#define TPB     256                     // threads per block
#define WARMT   8                       // first 8 threads = 512-sample warm region
#define OUTB    ((TPB - WARMT) * SEG)   // 15872 output samples per block

// Exact-by-linearity chunked IIR:
//  pass A: each thread scans its 64 samples from ZERO y-state (x kept in regs),
//          yielding end-state p. FIR x-history is exact (feedforward).
//  scan : block-wide Hillis-Steele over affine maps s' = A^64 s + p, with
//          constant matrices A^(64*2^k) (repeated squaring; entries decay ~r^64).
//  pass B: re-scan the registered samples from the exact initial state, store.
// Cross-block coupling: 512-sample warm region (zero-state transient ~6e-4).
__global__ __launch_bounds__(TPB, 4) void bandpass_kernel(
    const float* __restrict__ x,
    const int* __restrict__ sr_p,
    const float* __restrict__ fl_p,
    const float* __restrict__ fh_p,
    float* __restrict__ out)
{
    __shared__ float4 sscan[TPB];   // (lp_y1, lp_y2, hp_y1, hp_y2)

    const int tid = threadIdx.x;
    const int seq = blockIdx.y;
    const int bx  = blockIdx.x;

    // ---- biquad coefficients (double, cast to float) ----
    const double sr = (double)sr_p[0];
    const double twoQ = 2.0 * 0.707;

    double w0 = 2.0 * M_PI * (double)fl_p[0] / sr;
    double cw = cos(w0), al = sin(w0) / twoQ, a0 = 1.0 + al;
    const float  lb0   = (float)(((1.0 - cw) * 0.5) / a0);
    const float  lb1   = (float)((1.0 - cw) / a0);
    const float  lb2   = lb0;
    const double lna1d = (2.0 * cw) / a0;        // = -a1/a0
    const double lna2d = -(1.0 - al) / a0;       // = -a2/a0
    const float  lna1  = (float)lna1d, lna2 = (float)lna2d;

    w0 = 2.0 * M_PI * (double)fh_p[0] / sr;
    cw = cos(w0); al = sin(w0) / twoQ; a0 = 1.0 + al;
    const float  hb0   = (float)(((1.0 + cw) * 0.5) / a0);
    const float  hb1   = (float)(-(1.0 + cw) / a0);
    const float  hb2   = hb0;
    const double hna1d = (2.0 * cw) / a0;
    const double hna2d = -(1.0 - al) / a0;
    const float  hna1  = (float)hna1d, hna2 = (float)hna2d;

    // ---- A^64 per filter (double repeated squaring; A = [[na1,na2],[1,0]]) ----
    double l00 = lna1d, l01 = lna2d, l10 = 1.0, l11 = 0.0;
#pragma unroll
    for (int i = 0; i < 6; ++i) {
        double t00 = l00*l00 + l01*l10, t01 = l00*l01 + l01*l11;
        double t10 = l10*l00 + l11*l10, t11 = l10*l01 + l11*l11;
        l00 = t00; l01 = t01; l10 = t10; l11 = t11;
    }
    double h00 = hna1d, h01 = hna2d, h10 = 1.0, h11 = 0.0;
#pragma unroll
    for (int i = 0; i < 6; ++i) {
        double t00 = h00*h00 + h01*h10, t01 = h00*h01 + h01*h11;
        double t10 = h10*h00 + h11*h10, t11 = h10*h01 + h11*h11;
        h00 = t00; h01 = t01; h10 = t10; h11 = t11;
    }

    const float* __restrict__ xs = x   + (size_t)seq * T_LEN;
    float*       __restrict__ os = out + (size_t)seq * T_LEN;

    const int s0 = bx * OUTB - WARMT * SEG + tid * SEG;   // segment start (mult of 64)

    // ---- load 64 samples into registers (guarded at sequence edges) ----
    float4 xr[16];
    if (s0 >= 0 && s0 + SEG <= T_LEN) {
#pragma unroll
        for (int i = 0; i < 16; ++i) xr[i] = *(const float4*)(xs + s0 + 4*i);
    } else {
#pragma unroll
        for (int i = 0; i < 16; ++i) {
            float v[4];
#pragma unroll
            for (int k = 0; k < 4; ++k) {
                const int g = s0 + 4*i + k;
                v[k] = (g >= 0 && g < T_LEN) ? xs[g] : 0.f;
            }
            xr[i] = make_float4(v[0], v[1], v[2], v[3]);
        }
    }
    const float xh1 = (s0-1 >= 0 && s0-1 < T_LEN) ? xs[s0-1] : 0.f;
    const float xh2 = (s0-2 >= 0 && s0-2 < T_LEN) ? xs[s0-2] : 0.f;

    // ---- pass A: zero-state scan, end state only ----
    float x1 = xh1, x2 = xh2;
    float ly1 = 0.f, ly2 = 0.f, hy1 = 0.f, hy2 = 0.f;
#pragma unroll
    for (int i = 0; i < 16; ++i) {
        const float xv[4] = {xr[i].x, xr[i].y, xr[i].z, xr[i].w};
#pragma unroll
        for (int k = 0; k < 4; ++k) {
            const float xc  = xv[k];
            const float ffl = fmaf(lb0, xc, fmaf(lb1, x1, lb2 * x2));
            const float yl  = fmaf(lna2, ly2, fmaf(lna1, ly1, ffl));
            const float ffh = fmaf(hb0, xc, fmaf(hb1, x1, hb2 * x2));
            const float yh  = fmaf(hna2, hy2, fmaf(hna1, hy1, ffh));
            ly2 = ly1; ly1 = yl; hy2 = hy1; hy1 = yh;
            x2 = x1; x1 = xc;
        }
    }

    // ---- block scan over affine maps (8 steps, constant matrices) ----
    float4 p = make_float4(ly1, ly2, hy1, hy2);
    float ml00 = (float)l00, ml01 = (float)l01, ml10 = (float)l10, ml11 = (float)l11;
    float mh00 = (float)h00, mh01 = (float)h01, mh10 = (float)h10, mh11 = (float)h11;

    for (int k = 0; k < 8; ++k) {
        sscan[tid] = p;
        __syncthreads();
        const int j = tid - (1 << k);
        const float4 q = (j >= 0) ? sscan[j] : make_float4(0.f, 0.f, 0.f, 0.f);
        __syncthreads();
        p.x = fmaf(ml00, q.x, fmaf(ml01, q.y, p.x));
        p.y = fmaf(ml10, q.x, fmaf(ml11, q.y, p.y));
        p.z = fmaf(mh00, q.z, fmaf(mh01, q.w, p.z));
        p.w = fmaf(mh10, q.z, fmaf(mh11, q.w, p.w));
        // M <- M*M
        float t00 = fmaf(ml00, ml00, ml01*ml10), t01 = fmaf(ml00, ml01, ml01*ml11);
        float t10 = fmaf(ml10, ml00, ml11*ml10), t11 = fmaf(ml10, ml01, ml11*ml11);
        ml00 = t00; ml01 = t01; ml10 = t10; ml11 = t11;
        t00 = fmaf(mh00, mh00, mh01*mh10); t01 = fmaf(mh00, mh01, mh01*mh11);
        t10 = fmaf(mh10, mh00, mh11*mh10); t11 = fmaf(mh10, mh01, mh11*mh11);
        mh00 = t00; mh01 = t01; mh10 = t10; mh11 = t11;
    }
    sscan[tid] = p;                       // inclusive result
    __syncthreads();
    const float4 sx = (tid > 0) ? sscan[tid-1] : make_float4(0.f, 0.f, 0.f, 0.f);

    // ---- pass B: re-scan from exact initial state, store outputs ----
    if (tid >= WARMT && s0 < T_LEN) {
        float bx1 = xh1, bx2 = xh2;
        float Ly1 = sx.x, Ly2 = sx.y, Hy1 = sx.z, Hy2 = sx.w;
        const bool full = (s0 + SEG <= T_LEN);
#pragma unroll
        for (int i = 0; i < 16; ++i) {
            const float xv[4] = {xr[i].x, xr[i].y, xr[i].z, xr[i].w};
            float o[4];
#pragma unroll
            for (int k = 0; k < 4; ++k) {
                const float xc  = xv[k];
                const float ffl = fmaf(lb0, xc, fmaf(lb1, bx1, lb2 * bx2));
                const float yl  = fmaf(lna2, Ly2, fmaf(lna1, Ly1, ffl));
                const float ffh = fmaf(hb0, xc, fmaf(hb1, bx1, hb2 * bx2));
                const float yh  = fmaf(hna2, Hy2, fmaf(hna1, Hy1, ffh));
                Ly2 = Ly1; Ly1 = yl; Hy2 = Hy1; Hy1 = yh;
                bx2 = bx1; bx1 = xc;
                o[k] = yl - yh;
            }
            if (full) {
                *(float4*)(os + s0 + 4*i) = make_float4(o[0], o[1], o[2], o[3]);
            } else {
#pragma unroll
                for (int k = 0; k < 4; ++k) {
                    const int g = s0 + 4*i + k;
                    if (g < T_LEN) os[g] = o[k];
                }
            }
        }
    }
}

extern "C" void kernel_launch(void* const* d_in, const int* in_sizes, int n_in,
                              void* d_out, int out_size, void* d_ws, size_t ws_size,
                              hipStream_t stream) {
    const float* x  = (const float*)d_in[0];
    const int*   sr = (const int*)d_in[1];
    const float* fl = (const float*)d_in[2];
    const float* fh = (const float*)d_in[3];
    float* outp = (float*)d_out;

    const int nseq = in_sizes[0] / T_LEN;                 // 64
    const int bxn  = (T_LEN + OUTB - 1) / OUTB;           // 14

    dim3 block(TPB);
    dim3 grid(bxn, nseq);
    hipLaunchKernelGGL(bandpass_kernel, grid, block, 0, stream,
                       x, sr, fl, fh, outp);
}

// Round 5
// 128.875 us; speedup vs baseline: 1.9768x; 1.2045x over previous
//
#include <hip/hip_runtime.h>
#include <math.h>

#define T_LEN  220500
#define SEG    64                        // samples per lane-segment
#define TPB    256                       // 4 waves per block
#define WPB    4
#define WARML  8                         // warm lanes per wave (512-sample warmup)
#define WOUT   ((64 - WARML) * SEG)      // 3584 output samples per wave
#define BOUT   (WPB * WOUT)              // 14336 output samples per block
#define PRE    (WARML * SEG + 4)         // 516 staged samples before block output
#define RSAMP  (BOUT + PRE)              // 14852 staged samples per block
#define SLOT(j) ((j) + ((((j) >> 6)) << 2))   // +4 words/64: keeps f4 align, spreads banks
#define LDSW   (SLOT(RSAMP - 1) + 1)     // 15780 floats = 63.1 KB -> 2 blocks/CU

// Per wave: 64 lanes x 64-sample segments. Pass A scans each segment from zero
// y-state (exact FIR history from LDS). A 4-step shfl_up affine scan with
// constant matrices A^(64*2^k) composes states over a 16-segment (1024-sample)
// window -- numerically exact since |A^1024| ~ 1e-9 (poles r <= 0.9801).
// First 8 lanes/wave are warm (512-sample zero-state transient ~2e-4 << thr).
// All global I/O is coalesced float4 via one in-place LDS buffer.
__global__ __launch_bounds__(TPB, 2) void bandpass_kernel(
    const float* __restrict__ x,
    const int* __restrict__ sr_p,
    const float* __restrict__ fl_p,
    const float* __restrict__ fh_p,
    float* __restrict__ out)
{
    __shared__ float lds[LDSW];

    const int tid  = threadIdx.x;
    const int lane = tid & 63;
    const int wv   = tid >> 6;
    const int seq  = blockIdx.y;
    const int bxi  = blockIdx.x;

    // ---- fp32 biquad coefficients (reference computes them in fp32 too) ----
    const float sr   = (float)sr_p[0];
    const float twoQ = (float)(2.0 * 0.707);

    float w0 = (float)(2.0 * M_PI) * fl_p[0] / sr;
    float cw = cosf(w0);
    float al = sinf(w0) / twoQ;
    float a0 = 1.0f + al;
    const float lb0  = (1.0f - cw) * 0.5f / a0;
    const float lb1  = (1.0f - cw) / a0;
    const float lb2  = lb0;
    const float lna1 = 2.0f * cw / a0;        // = -a1/a0
    const float lna2 = -(1.0f - al) / a0;     // = -a2/a0

    w0 = (float)(2.0 * M_PI) * fh_p[0] / sr;
    cw = cosf(w0);
    al = sinf(w0) / twoQ;
    a0 = 1.0f + al;
    const float hb0  = (1.0f + cw) * 0.5f / a0;
    const float hb1  = -(1.0f + cw) / a0;
    const float hb2  = hb0;
    const float hna1 = 2.0f * cw / a0;
    const float hna2 = -(1.0f - al) / a0;

    // ---- scan matrices A^(64*2^k), k=0..3 (A=[[na1,na2],[1,0]], fp32 squaring) ----
    float4 Ml[4], Mh[4];
    {
        float a = lna1, b = lna2, c = 1.0f, d = 0.0f;
#pragma unroll
        for (int i = 0; i < 6; ++i) {
            float t0 = fmaf(a, a, b * c), t1 = fmaf(a, b, b * d);
            float t2 = fmaf(c, a, d * c), t3 = fmaf(c, b, d * d);
            a = t0; b = t1; c = t2; d = t3;
        }
        Ml[0] = make_float4(a, b, c, d);
#pragma unroll
        for (int k = 1; k < 4; ++k) {
            float t0 = fmaf(a, a, b * c), t1 = fmaf(a, b, b * d);
            float t2 = fmaf(c, a, d * c), t3 = fmaf(c, b, d * d);
            a = t0; b = t1; c = t2; d = t3;
            Ml[k] = make_float4(a, b, c, d);
        }
        a = hna1; b = hna2; c = 1.0f; d = 0.0f;
#pragma unroll
        for (int i = 0; i < 6; ++i) {
            float t0 = fmaf(a, a, b * c), t1 = fmaf(a, b, b * d);
            float t2 = fmaf(c, a, d * c), t3 = fmaf(c, b, d * d);
            a = t0; b = t1; c = t2; d = t3;
        }
        Mh[0] = make_float4(a, b, c, d);
#pragma unroll
        for (int k = 1; k < 4; ++k) {
            float t0 = fmaf(a, a, b * c), t1 = fmaf(a, b, b * d);
            float t2 = fmaf(c, a, d * c), t3 = fmaf(c, b, d * d);
            a = t0; b = t1; c = t2; d = t3;
            Mh[k] = make_float4(a, b, c, d);
        }
    }

    const float* __restrict__ xs = x   + (size_t)seq * T_LEN;
    float*       __restrict__ os = out + (size_t)seq * T_LEN;

    const int G0 = bxi * BOUT - PRE;          // global sample at region coord 0 (mult of 4)

    // ---- stage input, coalesced float4 (OOB -> 0) ----
    for (int j4 = tid; j4 < RSAMP / 4; j4 += TPB) {
        const int j = j4 * 4;
        const int g = G0 + j;
        float4 v;
        if (g >= 0 && g + 4 <= T_LEN) {
            v = *(const float4*)(xs + g);
        } else {
            float e[4];
#pragma unroll
            for (int k = 0; k < 4; ++k) {
                const int gg = g + k;
                e[k] = (gg >= 0 && gg < T_LEN) ? xs[gg] : 0.f;
            }
            v = make_float4(e[0], e[1], e[2], e[3]);
        }
        *(float4*)&lds[SLOT(j)] = v;
    }
    __syncthreads();

    // region coord of this lane's segment start
    const int jb = 4 + wv * WOUT + lane * SEG;

    const float xh1 = lds[SLOT(jb - 1)];
    const float xh2 = lds[SLOT(jb - 2)];

    // ---- pass A: zero-state scan of own segment ----
    float x1 = xh1, x2 = xh2;
    float ly1 = 0.f, ly2 = 0.f, hy1 = 0.f, hy2 = 0.f;
#pragma unroll
    for (int i = 0; i < 16; ++i) {
        const float4 xv = *(const float4*)&lds[SLOT(jb + 4 * i)];
        const float xa[4] = {xv.x, xv.y, xv.z, xv.w};
#pragma unroll
        for (int k = 0; k < 4; ++k) {
            const float xc  = xa[k];
            const float ffl = fmaf(lb0, xc, fmaf(lb1, x1, lb2 * x2));
            const float yl  = fmaf(lna2, ly2, fmaf(lna1, ly1, ffl));
            const float ffh = fmaf(hb0, xc, fmaf(hb1, x1, hb2 * x2));
            const float yh  = fmaf(hna2, hy2, fmaf(hna1, hy1, ffh));
            ly2 = ly1; ly1 = yl; hy2 = hy1; hy1 = yh;
            x2 = x1; x1 = xc;
        }
    }

    // ---- 4-step shfl_up affine scan within wave (no barriers) ----
    float4 p = make_float4(ly1, ly2, hy1, hy2);
#pragma unroll
    for (int k = 0; k < 4; ++k) {
        const int d = 1 << k;
        float qx = __shfl_up(p.x, d, 64);
        float qy = __shfl_up(p.y, d, 64);
        float qz = __shfl_up(p.z, d, 64);
        float qw = __shfl_up(p.w, d, 64);
        if (lane < d) { qx = 0.f; qy = 0.f; qz = 0.f; qw = 0.f; }
        p.x = fmaf(Ml[k].x, qx, fmaf(Ml[k].y, qy, p.x));
        p.y = fmaf(Ml[k].z, qx, fmaf(Ml[k].w, qy, p.y));
        p.z = fmaf(Mh[k].x, qz, fmaf(Mh[k].y, qw, p.z));
        p.w = fmaf(Mh[k].z, qz, fmaf(Mh[k].w, qw, p.w));
    }
    // exclusive prefix = inclusive of lane-1
    float sx0 = __shfl_up(p.x, 1, 64);
    float sx1 = __shfl_up(p.y, 1, 64);
    float sx2 = __shfl_up(p.z, 1, 64);
    float sx3 = __shfl_up(p.w, 1, 64);
    if (lane == 0) { sx0 = 0.f; sx1 = 0.f; sx2 = 0.f; sx3 = 0.f; }

    // all cross-lane x reads (pass A, xh) done -> safe to overwrite in place
    __syncthreads();

    // ---- pass B: re-scan from exact state, write outputs in place ----
    if (lane >= WARML) {
        float bx1 = xh1, bx2 = xh2;
        float Ly1 = sx0, Ly2 = sx1, Hy1 = sx2, Hy2 = sx3;
#pragma unroll
        for (int i = 0; i < 16; ++i) {
            float* sp = &lds[SLOT(jb + 4 * i)];
            const float4 xv = *(const float4*)sp;
            const float xa[4] = {xv.x, xv.y, xv.z, xv.w};
            float o[4];
#pragma unroll
            for (int k = 0; k < 4; ++k) {
                const float xc  = xa[k];
                const float ffl = fmaf(lb0, xc, fmaf(lb1, bx1, lb2 * bx2));
                const float yl  = fmaf(lna2, Ly2, fmaf(lna1, Ly1, ffl));
                const float ffh = fmaf(hb0, xc, fmaf(hb1, bx1, hb2 * bx2));
                const float yh  = fmaf(hna2, Hy2, fmaf(hna1, Hy1, ffh));
                Ly2 = Ly1; Ly1 = yl; Hy2 = Hy1; Hy1 = yh;
                bx2 = bx1; bx1 = xc;
                o[k] = yl - yh;
            }
            *(float4*)sp = make_float4(o[0], o[1], o[2], o[3]);
        }
    }
    __syncthreads();

    // ---- flush outputs, coalesced float4 ----
    for (int f4 = tid; f4 < BOUT / 4; f4 += TPB) {
        const int j = PRE + 4 * f4;
        const int g = G0 + j;                  // = bxi*BOUT + 4*f4, mult of 4
        if (g < T_LEN) {                       // T_LEN mult of 4 -> no partials
            *(float4*)(os + g) = *(const float4*)&lds[SLOT(j)];
        }
    }
}

extern "C" void kernel_launch(void* const* d_in, const int* in_sizes, int n_in,
                              void* d_out, int out_size, void* d_ws, size_t ws_size,
                              hipStream_t stream) {
    const float* x  = (const float*)d_in[0];
    const int*   sr = (const int*)d_in[1];
    const float* fl = (const float*)d_in[2];
    const float* fh = (const float*)d_in[3];
    float* outp = (float*)d_out;

    const int nseq = in_sizes[0] / T_LEN;                 // 64
    const int bxn  = (T_LEN + BOUT - 1) / BOUT;           // 16

    dim3 block(TPB);
    dim3 grid(bxn, nseq);
    hipLaunchKernelGGL(bandpass_kernel, grid, block, 0, stream,
                       x, sr, fl, fh, outp);
}

// Round 7
// 118.405 us; speedup vs baseline: 2.1516x; 1.0884x over previous
//
#include <hip/hip_runtime.h>
#include <math.h>

#define T_LEN  220500
#define SEG    64                          // samples per lane
#define TPB    64                          // one wave per block
#define WARML  8                           // warm lanes (512-sample zero-state warmup)
#define WOUT   ((64 - WARML) * SEG)        // 3584 output samples per wave/window
#define WSLOTS (WOUT / 4)                  // 896 float4 slots in LDS
#define NWIN   ((T_LEN + WOUT - 1) / WOUT) // 62 windows per sequence

// XOR swizzle on float4-slot index: conflict-free for both the pass-B write
// pattern (lane l -> slots (l-8)*16+i) and the flush read pattern
// (lane m -> slots 64k+m). Flips only bits 0..2, so stays within each
// 16-slot group (and within [0, WSLOTS)).
__device__ __forceinline__ int swz(int s) { return s ^ ((s >> 4) & 7); }

// One wave per 3584-sample output window. 16 independent clamped float4
// loads -> registers (single vmcnt drain). Pass A: zero-state scan of own
// 64-sample segment. 4-step __shfl_up affine scan composes states (window
// of 1024 samples; |A^1024| ~ 1e-9, poles r <= 0.9801 -> numerically exact).
// First 8 lanes are warm-up (512-sample zero-state transient ~2e-4 << thr).
// Pass B re-scans from the exact state, writes to swizzled LDS; wave-local
// flush stores coalesced float4.
__global__ __launch_bounds__(TPB) void bandpass_kernel(
    const float* __restrict__ x,
    const int* __restrict__ sr_p,
    const float* __restrict__ fl_p,
    const float* __restrict__ fh_p,
    float* __restrict__ out)
{
    __shared__ float4 lds4[WSLOTS];

    const int lane = threadIdx.x;          // 0..63
    const int win  = blockIdx.x;           // 0..NWIN-1
    const int seq  = blockIdx.y;

    // ---- fp32 biquad coefficients (reference computes in fp32 too) ----
    const float sr   = (float)sr_p[0];
    const float twoQ = (float)(2.0 * 0.707);

    float w0 = (float)(2.0 * M_PI) * fl_p[0] / sr;
    float cw = cosf(w0);
    float al = sinf(w0) / twoQ;
    float a0 = 1.0f + al;
    const float lb0  = (1.0f - cw) * 0.5f / a0;
    const float lb1  = (1.0f - cw) / a0;
    const float lb2  = lb0;
    const float lna1 = 2.0f * cw / a0;        // = -a1/a0
    const float lna2 = -(1.0f - al) / a0;     // = -a2/a0

    w0 = (float)(2.0 * M_PI) * fh_p[0] / sr;
    cw = cosf(w0);
    al = sinf(w0) / twoQ;
    a0 = 1.0f + al;
    const float hb0  = (1.0f + cw) * 0.5f / a0;
    const float hb1  = -(1.0f + cw) / a0;
    const float hb2  = hb0;
    const float hna1 = 2.0f * cw / a0;
    const float hna2 = -(1.0f - al) / a0;

    const float* __restrict__ xs = x   + (size_t)seq * T_LEN;
    float*       __restrict__ os = out + (size_t)seq * T_LEN;

    const int Wbase = win * WOUT;
    const int s0    = Wbase - WARML * SEG + lane * SEG;   // multiple of 4

    // ---- 16 independent clamped float4 loads (one vmcnt drain) ----
    // s0 and T_LEN are multiples of 4 -> each float4 is fully in or fully out.
    float4 xr[16];
#pragma unroll
    for (int i = 0; i < 16; ++i) {
        const int g  = s0 + 4 * i;
        const int gc = min(max(g, 0), T_LEN - 4);
        float4 v = *(const float4*)(xs + gc);
        if (g < 0 || g >= T_LEN) v = make_float4(0.f, 0.f, 0.f, 0.f);
        xr[i] = v;
    }

    // x-history from neighbor lane's registers (exact); lane 0 loads guarded.
    float xh1 = __shfl_up(xr[15].w, 1, 64);
    float xh2 = __shfl_up(xr[15].z, 1, 64);
    if (lane == 0) {
        xh1 = (s0 >= 1) ? xs[s0 - 1] : 0.f;
        xh2 = (s0 >= 2) ? xs[s0 - 2] : 0.f;
    }

    // ---- pass A: zero-state scan of own segment ----
    float x1 = xh1, x2 = xh2;
    float ly1 = 0.f, ly2 = 0.f, hy1 = 0.f, hy2 = 0.f;
#pragma unroll
    for (int i = 0; i < 16; ++i) {
        const float xa[4] = {xr[i].x, xr[i].y, xr[i].z, xr[i].w};
#pragma unroll
        for (int k = 0; k < 4; ++k) {
            const float xc  = xa[k];
            const float ffl = fmaf(lb0, xc, fmaf(lb1, x1, lb2 * x2));
            const float yl  = fmaf(lna2, ly2, fmaf(lna1, ly1, ffl));
            const float ffh = fmaf(hb0, xc, fmaf(hb1, x1, hb2 * x2));
            const float yh  = fmaf(hna2, hy2, fmaf(hna1, hy1, ffh));
            ly2 = ly1; ly1 = yl; hy2 = hy1; hy1 = yh;
            x2 = x1; x1 = xc;
        }
    }

    // ---- A^64 via 6 fp32 squarings (A = [[na1,na2],[1,0]]) ----
    float la = lna1, lb = lna2, lc = 1.0f, ld = 0.0f;
    float ha = hna1, hb = hna2, hc = 1.0f, hd = 0.0f;
#pragma unroll
    for (int i = 0; i < 6; ++i) {
        float t0 = fmaf(la, la, lb * lc), t1 = fmaf(la, lb, lb * ld);
        float t2 = fmaf(lc, la, ld * lc), t3 = fmaf(lc, lb, ld * ld);
        la = t0; lb = t1; lc = t2; ld = t3;
        t0 = fmaf(ha, ha, hb * hc); t1 = fmaf(ha, hb, hb * hd);
        t2 = fmaf(hc, ha, hd * hc); t3 = fmaf(hc, hb, hd * hd);
        ha = t0; hb = t1; hc = t2; hd = t3;
    }

    // ---- 4-step shfl_up affine scan (distances 1,2,4,8 segments) ----
    float4 p = make_float4(ly1, ly2, hy1, hy2);
#pragma unroll
    for (int k = 0; k < 4; ++k) {
        const int d = 1 << k;
        float qx = __shfl_up(p.x, d, 64);
        float qy = __shfl_up(p.y, d, 64);
        float qz = __shfl_up(p.z, d, 64);
        float qw = __shfl_up(p.w, d, 64);
        if (lane < d) { qx = 0.f; qy = 0.f; qz = 0.f; qw = 0.f; }
        p.x = fmaf(la, qx, fmaf(lb, qy, p.x));
        p.y = fmaf(lc, qx, fmaf(ld, qy, p.y));
        p.z = fmaf(ha, qz, fmaf(hb, qw, p.z));
        p.w = fmaf(hc, qz, fmaf(hd, qw, p.w));
        // M <- M*M  (A^(64*2^(k+1)))
        float t0 = fmaf(la, la, lb * lc), t1 = fmaf(la, lb, lb * ld);
        float t2 = fmaf(lc, la, ld * lc), t3 = fmaf(lc, lb, ld * ld);
        la = t0; lb = t1; lc = t2; ld = t3;
        t0 = fmaf(ha, ha, hb * hc); t1 = fmaf(ha, hb, hb * hd);
        t2 = fmaf(hc, ha, hd * hc); t3 = fmaf(hc, hb, hd * hd);
        ha = t0; hb = t1; hc = t2; hd = t3;
    }
    // exclusive prefix = inclusive of lane-1
    float sx0 = __shfl_up(p.x, 1, 64);
    float sx1 = __shfl_up(p.y, 1, 64);
    float sx2 = __shfl_up(p.z, 1, 64);
    float sx3 = __shfl_up(p.w, 1, 64);
    if (lane == 0) { sx0 = 0.f; sx1 = 0.f; sx2 = 0.f; sx3 = 0.f; }

    // ---- pass B: re-scan from exact state, write swizzled LDS ----
    if (lane >= WARML) {
        float bx1 = xh1, bx2 = xh2;
        float Ly1 = sx0, Ly2 = sx1, Hy1 = sx2, Hy2 = sx3;
        const int sb = (lane - WARML) * 16;
#pragma unroll
        for (int i = 0; i < 16; ++i) {
            const float xa[4] = {xr[i].x, xr[i].y, xr[i].z, xr[i].w};
            float o[4];
#pragma unroll
            for (int k = 0; k < 4; ++k) {
                const float xc  = xa[k];
                const float ffl = fmaf(lb0, xc, fmaf(lb1, bx1, lb2 * bx2));
                const float yl  = fmaf(lna2, Ly2, fmaf(lna1, Ly1, ffl));
                const float ffh = fmaf(hb0, xc, fmaf(hb1, bx1, hb2 * bx2));
                const float yh  = fmaf(hna2, Hy2, fmaf(hna1, Hy1, ffh));
                Ly2 = Ly1; Ly1 = yl; Hy2 = Hy1; Hy1 = yh;
                bx2 = bx1; bx1 = xc;
                o[k] = yl - yh;
            }
            lds4[swz(sb + i)] = make_float4(o[0], o[1], o[2], o[3]);
        }
    }

    // LDS write -> cross-lane read ordering. Single-wave block: this is one
    // cheap s_barrier + waitcnt; avoids relying on inline-asm ordering.
    __syncthreads();

    // ---- flush: coalesced float4 stores ----
#pragma unroll
    for (int k = 0; k < WSLOTS / 64; ++k) {   // 14
        const int slot = 64 * k + lane;
        const float4 v = lds4[swz(slot)];
        const int g = Wbase + 4 * slot;        // multiple of 4; T_LEN mult of 4
        if (g < T_LEN) *(float4*)(os + g) = v;
    }
}

extern "C" void kernel_launch(void* const* d_in, const int* in_sizes, int n_in,
                              void* d_out, int out_size, void* d_ws, size_t ws_size,
                              hipStream_t stream) {
    const float* x  = (const float*)d_in[0];
    const int*   sr = (const int*)d_in[1];
    const float* fl = (const float*)d_in[2];
    const float* fh = (const float*)d_in[3];
    float* outp = (float*)d_out;

    const int nseq = in_sizes[0] / T_LEN;      // 64

    dim3 block(TPB);
    dim3 grid(NWIN, nseq);                     // 62 x 64 = 3968 waves
    hipLaunchKernelGGL(bandpass_kernel, grid, block, 0, stream,
                       x, sr, fl, fh, outp);
}